// Round 9
// baseline (293.996 us; speedup 1.0000x reference)
//
#include <hip/hip_runtime.h>
#include <hip/hip_cooperative_groups.h>

#define DIN  128
#define DOUT 32

typedef __attribute__((ext_vector_type(8))) short bf16x8;   // 8 bf16 = 4 VGPRs
typedef __attribute__((ext_vector_type(4))) float f32x4;

// f32 -> bf16 (RNE), manual
__device__ __forceinline__ unsigned int f2b(float f) {
    unsigned int u = __float_as_uint(f);
    return (u + 0x7fffu + ((u >> 16) & 1u)) >> 16;
}
// packed f32x2 -> bf16x2 (RNE), hardware
__device__ __forceinline__ unsigned int cvtpk(float lo, float hi) {
    unsigned int r;
    asm("v_cvt_pk_bf16_f32 %0, %1, %2" : "=v"(r) : "v"(lo), "v"(hi));
    return r;
}

union FragU { bf16x8 v; unsigned int u[4]; };

// ---- B fragments from W (built once; W is L1/L2-hot) -----------------------
__device__ __forceinline__ void build_bfrag(const float* __restrict__ W,
                                            int lane, bf16x8 bfrag[2][4])
{
    const int lr = lane & 15, kh = lane >> 4;
    #pragma unroll
    for (int ct = 0; ct < 2; ++ct) {
        #pragma unroll
        for (int ks = 0; ks < 4; ++ks) {
            const int col = ct * 16 + lr;
            const int k0  = ks * 32 + kh * 8;
            float f[8];
            #pragma unroll
            for (int j = 0; j < 8; ++j) f[j] = W[(k0 + j) * DOUT + col];
            FragU fu;
            fu.u[0] = cvtpk(f[0], f[1]); fu.u[1] = cvtpk(f[2], f[3]);
            fu.u[2] = cvtpk(f[4], f[5]); fu.u[3] = cvtpk(f[6], f[7]);
            bfrag[ct][ks] = fu.v;
        }
    }
}

// ---- one 16-row GEMM tile via MFMA; all 8 loads issued before any cvt ------
__device__ __forceinline__ void gemm_tile(const float* __restrict__ H,
                                          unsigned short* __restrict__ HWb,
                                          int rb, int lane,
                                          const bf16x8 bfrag[2][4])
{
    const int lr = lane & 15, kh = lane >> 4;
    const float* __restrict__ hp = H + (size_t)(rb + lr) * DIN;

    float4 raw[8];
    #pragma unroll
    for (int ks = 0; ks < 4; ++ks) {
        raw[2*ks]   = *reinterpret_cast<const float4*>(hp + ks * 32 + kh * 8);
        raw[2*ks+1] = *reinterpret_cast<const float4*>(hp + ks * 32 + kh * 8 + 4);
    }
    bf16x8 afrag[4];
    #pragma unroll
    for (int ks = 0; ks < 4; ++ks) {
        FragU fu;
        fu.u[0] = cvtpk(raw[2*ks].x,   raw[2*ks].y);
        fu.u[1] = cvtpk(raw[2*ks].z,   raw[2*ks].w);
        fu.u[2] = cvtpk(raw[2*ks+1].x, raw[2*ks+1].y);
        fu.u[3] = cvtpk(raw[2*ks+1].z, raw[2*ks+1].w);
        afrag[ks] = fu.v;
    }

    f32x4 acc[2] = {(f32x4){0.f,0.f,0.f,0.f}, (f32x4){0.f,0.f,0.f,0.f}};
    #pragma unroll
    for (int ct = 0; ct < 2; ++ct)
        #pragma unroll
        for (int ks = 0; ks < 4; ++ks)
            acc[ct] = __builtin_amdgcn_mfma_f32_16x16x32_bf16(
                afrag[ks], bfrag[ct][ks], acc[ct], 0, 0, 0);

    #pragma unroll
    for (int ct = 0; ct < 2; ++ct)
        #pragma unroll
        for (int r = 0; r < 4; ++r)
            HWb[(size_t)(rb + kh * 4 + r) * DOUT + ct * 16 + lr] =
                (unsigned short)f2b(acc[ct][r]);
}

// ---- SpMM row body: 8 threads/row, 4 cols each; 16 gathers force-batched ---
__device__ __forceinline__ void spmm_row(const unsigned short* __restrict__ HWb,
                                         const int* __restrict__ rowPtr,
                                         const int* __restrict__ colIdx,
                                         const float* __restrict__ val,
                                         float* __restrict__ out,
                                         int n, int row, int cg)
{
    if (row >= n) return;
    const uint2* __restrict__ tbl = reinterpret_cast<const uint2*>(HWb);
    const int start = rowPtr[row];
    const int end   = rowPtr[row + 1];
    float a0 = 0.f, a1 = 0.f, a2 = 0.f, a3 = 0.f;

    #define ACC(G, V)                                                        \
        a0 = fmaf(V, __uint_as_float((G).x << 16), a0);                      \
        a1 = fmaf(V, __uint_as_float((G).x & 0xffff0000u), a1);              \
        a2 = fmaf(V, __uint_as_float((G).y << 16), a2);                      \
        a3 = fmaf(V, __uint_as_float((G).y & 0xffff0000u), a3);

    if (end - start == 16 && (start & 3) == 0) {
        const int4*   ci = reinterpret_cast<const int4*>(colIdx + start);
        const float4* vv = reinterpret_cast<const float4*>(val + start);
        const int4   c0 = ci[0], c1 = ci[1], c2 = ci[2], c3 = ci[3];
        const float4 v0 = vv[0], v1 = vv[1], v2 = vv[2], v3 = vv[3];
        // all 16 gathers issued before any consumption
        const uint2 g0  = tbl[c0.x * 8 + cg], g1  = tbl[c0.y * 8 + cg];
        const uint2 g2  = tbl[c0.z * 8 + cg], g3  = tbl[c0.w * 8 + cg];
        const uint2 g4  = tbl[c1.x * 8 + cg], g5  = tbl[c1.y * 8 + cg];
        const uint2 g6  = tbl[c1.z * 8 + cg], g7  = tbl[c1.w * 8 + cg];
        const uint2 g8  = tbl[c2.x * 8 + cg], g9  = tbl[c2.y * 8 + cg];
        const uint2 g10 = tbl[c2.z * 8 + cg], g11 = tbl[c2.w * 8 + cg];
        const uint2 g12 = tbl[c3.x * 8 + cg], g13 = tbl[c3.y * 8 + cg];
        const uint2 g14 = tbl[c3.z * 8 + cg], g15 = tbl[c3.w * 8 + cg];
        // reference accumulation order (ascending edge)
        ACC(g0,  v0.x) ACC(g1,  v0.y) ACC(g2,  v0.z) ACC(g3,  v0.w)
        ACC(g4,  v1.x) ACC(g5,  v1.y) ACC(g6,  v1.z) ACC(g7,  v1.w)
        ACC(g8,  v2.x) ACC(g9,  v2.y) ACC(g10, v2.z) ACC(g11, v2.w)
        ACC(g12, v3.x) ACC(g13, v3.y) ACC(g14, v3.z) ACC(g15, v3.w)
    } else {
        for (int e = start; e < end; ++e) {
            const int   c = colIdx[e];
            const float v = val[e];
            const uint2 g = tbl[c * 8 + cg];
            ACC(g, v)
        }
    }
    #undef ACC

    reinterpret_cast<float4*>(out)[(size_t)row * 8 + cg] =
        make_float4(a0, a1, a2, a3);
}

// ---------------- Cooperative fused kernel ----------------------------------
// Phase 1: grid-stride 16-row GEMM tiles per wave. threadfence + grid.sync
// (agent fence -> L2 writeback; table visible across XCDs). Phase 2: SpMM.
__global__ __launch_bounds__(256, 4) void fused_coop_kernel(
    const float* __restrict__ H, const float* __restrict__ W,
    const int* __restrict__ rowPtr, const int* __restrict__ colIdx,
    const float* __restrict__ val, unsigned short* __restrict__ HWb,
    float* __restrict__ out, int n)
{
    const int lane = threadIdx.x & 63;
    const int w    = threadIdx.x >> 6;

    bf16x8 bfrag[2][4];
    build_bfrag(W, lane, bfrag);

    const int ntiles = (n + 15) >> 4;
    const int nwaves = gridDim.x * 4;
    for (int t = blockIdx.x * 4 + w; t < ntiles; t += nwaves) {
        int rb = t * 16;
        if (rb + 16 > n) rb = n - 16;   // overlap-recompute, identical values
        gemm_tile(H, HWb, rb, lane, bfrag);
    }

    __threadfence();                      // release: drain table to LLC
    cooperative_groups::this_grid().sync();
    __threadfence();                      // acquire side

    const int ngrp = (n + 31) >> 5;       // 32 rows per block-iteration
    for (int g = blockIdx.x; g < ngrp; g += gridDim.x)
        spmm_row(HWb, rowPtr, colIdx, val, out, n,
                 g * 32 + (threadIdx.x >> 3), threadIdx.x & 7);
}

// ---------------- Fallback pair (same bodies, two launches) -----------------
__global__ __launch_bounds__(256) void gemm_mfma_kernel(
    const float* __restrict__ H, const float* __restrict__ W,
    unsigned short* __restrict__ HWb, int n)
{
    const int lane = threadIdx.x & 63;
    const int w    = threadIdx.x >> 6;
    bf16x8 bfrag[2][4];
    build_bfrag(W, lane, bfrag);
    int rb = blockIdx.x * 64 + w * 16;
    if (rb + 16 > n) rb = n - 16;
    gemm_tile(H, HWb, rb, lane, bfrag);
}

__global__ __launch_bounds__(256) void spmm_kernel(
    const unsigned short* __restrict__ HWb, const int* __restrict__ rowPtr,
    const int* __restrict__ colIdx, const float* __restrict__ val,
    float* __restrict__ out, int n)
{
    const int gid = blockIdx.x * 256 + threadIdx.x;
    spmm_row(HWb, rowPtr, colIdx, val, out, n, gid >> 3, gid & 7);
}

// ---------------- Fallback: fused f32 (ws too small or n < 16) --------------
__global__ __launch_bounds__(256) void fused_kernel(
    const float* __restrict__ H, const float* __restrict__ W,
    const int* __restrict__ rowPtr, const int* __restrict__ colIdx,
    const float* __restrict__ val, float* __restrict__ out, int n)
{
    __shared__ float Wlds[DIN * DOUT];
    for (int i = threadIdx.x; i < DIN * DOUT; i += 256) Wlds[i] = W[i];
    __syncthreads();

    const int gid = blockIdx.x * 256 + threadIdx.x;
    const int row = gid >> 5;
    if (row >= n) return;
    const int c = gid & 31;

    const int start = rowPtr[row];
    const int end   = rowPtr[row + 1];
    float acc = 0.f;
    for (int e = start; e < end; ++e) {
        const int   cidx = colIdx[e];
        const float v    = val[e];
        const float* h = H + (size_t)cidx * DIN;
        float dot = 0.f;
        #pragma unroll 8
        for (int k = 0; k < DIN; ++k)
            dot = fmaf(h[k], Wlds[k * DOUT + c], dot);
        acc = fmaf(v, dot, acc);
    }
    out[(size_t)row * DOUT + c] = acc;
}

extern "C" void kernel_launch(void* const* d_in, const int* in_sizes, int n_in,
                              void* d_out, int out_size, void* d_ws, size_t ws_size,
                              hipStream_t stream)
{
    const float* H      = (const float*)d_in[0];
    const float* W      = (const float*)d_in[1];
    const int*   rowPtr = (const int*)d_in[2];
    const int*   colIdx = (const int*)d_in[3];
    const float* val    = (const float*)d_in[4];
    float*       out    = (float*)d_out;

    const int n = in_sizes[2] - 1;           // rowPtr has N+1 entries
    const size_t hw_bytes = (size_t)n * DOUT * sizeof(unsigned short);

    if (ws_size >= hw_bytes && n >= 16) {
        unsigned short* HWb = (unsigned short*)d_ws;

        // Try the cooperative fused kernel (1024 blocks = 4/CU co-resident).
        const float* Ha = H; const float* Wa = W;
        const int* rp = rowPtr; const int* cia = colIdx; const float* va = val;
        unsigned short* hb = HWb; float* oa = out; int na = n;
        void* args[] = {&Ha, &Wa, &rp, &cia, &va, &hb, &oa, &na};
        hipError_t err = hipLaunchCooperativeKernel(
            (const void*)fused_coop_kernel, dim3(1024), dim3(256), args, 0, stream);

        if (err != hipSuccess) {
            // Fallback: same bodies, two launches (implicit inter-kernel fence).
            gemm_mfma_kernel<<<(n + 63) / 64, 256, 0, stream>>>(H, W, HWb, n);
            const int spmm_blocks = (int)(((size_t)n * 8 + 255) / 256);
            spmm_kernel<<<spmm_blocks, 256, 0, stream>>>(HWb, rowPtr, colIdx, val, out, n);
        }
    } else {
        const int blocks = (int)(((size_t)n * DOUT + 255) / 256);
        fused_kernel<<<blocks, 256, 0, stream>>>(H, W, rowPtr, colIdx, val, out, n);
    }
}

// Round 10
// 38.084 us; speedup vs baseline: 7.7197x; 7.7197x over previous
//
#include <hip/hip_runtime.h>

#define DIN  128
#define DOUT 32

typedef __attribute__((ext_vector_type(8))) short bf16x8;   // 8 bf16 = 4 VGPRs
typedef __attribute__((ext_vector_type(4))) float f32x4;

// f32 -> bf16 (RNE), manual
__device__ __forceinline__ unsigned int f2b(float f) {
    unsigned int u = __float_as_uint(f);
    return (u + 0x7fffu + ((u >> 16) & 1u)) >> 16;
}
// packed f32x2 -> bf16x2 (RNE), hardware
__device__ __forceinline__ unsigned int cvtpk(float lo, float hi) {
    unsigned int r;
    asm("v_cvt_pk_bf16_f32 %0, %1, %2" : "=v"(r) : "v"(lo), "v"(hi));
    return r;
}

union FragU { bf16x8 v; unsigned int u[4]; };

// ---- B fragments from W (built once; W is L1/L2-hot) -----------------------
__device__ __forceinline__ void build_bfrag(const float* __restrict__ W,
                                            int lane, bf16x8 bfrag[2][4])
{
    const int lr = lane & 15, kh = lane >> 4;
    #pragma unroll
    for (int ct = 0; ct < 2; ++ct) {
        #pragma unroll
        for (int ks = 0; ks < 4; ++ks) {
            const int col = ct * 16 + lr;
            const int k0  = ks * 32 + kh * 8;
            float f[8];
            #pragma unroll
            for (int j = 0; j < 8; ++j) f[j] = W[(k0 + j) * DOUT + col];
            FragU fu;
            fu.u[0] = cvtpk(f[0], f[1]); fu.u[1] = cvtpk(f[2], f[3]);
            fu.u[2] = cvtpk(f[4], f[5]); fu.u[3] = cvtpk(f[6], f[7]);
            bfrag[ct][ks] = fu.v;
        }
    }
}

// ---- one 16-row GEMM tile via MFMA; all 8 loads issued before any cvt ------
__device__ __forceinline__ void gemm_tile(const float* __restrict__ H,
                                          unsigned short* __restrict__ HWb,
                                          int rb, int lane,
                                          const bf16x8 bfrag[2][4])
{
    const int lr = lane & 15, kh = lane >> 4;
    const float* __restrict__ hp = H + (size_t)(rb + lr) * DIN;

    float4 raw[8];
    #pragma unroll
    for (int ks = 0; ks < 4; ++ks) {
        raw[2*ks]   = *reinterpret_cast<const float4*>(hp + ks * 32 + kh * 8);
        raw[2*ks+1] = *reinterpret_cast<const float4*>(hp + ks * 32 + kh * 8 + 4);
    }
    bf16x8 afrag[4];
    #pragma unroll
    for (int ks = 0; ks < 4; ++ks) {
        FragU fu;
        fu.u[0] = cvtpk(raw[2*ks].x,   raw[2*ks].y);
        fu.u[1] = cvtpk(raw[2*ks].z,   raw[2*ks].w);
        fu.u[2] = cvtpk(raw[2*ks+1].x, raw[2*ks+1].y);
        fu.u[3] = cvtpk(raw[2*ks+1].z, raw[2*ks+1].w);
        afrag[ks] = fu.v;
    }

    f32x4 acc[2] = {(f32x4){0.f,0.f,0.f,0.f}, (f32x4){0.f,0.f,0.f,0.f}};
    #pragma unroll
    for (int ct = 0; ct < 2; ++ct)
        #pragma unroll
        for (int ks = 0; ks < 4; ++ks)
            acc[ct] = __builtin_amdgcn_mfma_f32_16x16x32_bf16(
                afrag[ks], bfrag[ct][ks], acc[ct], 0, 0, 0);

    #pragma unroll
    for (int ct = 0; ct < 2; ++ct)
        #pragma unroll
        for (int r = 0; r < 4; ++r)
            HWb[(size_t)(rb + kh * 4 + r) * DOUT + ct * 16 + lr] =
                (unsigned short)f2b(acc[ct][r]);
}

// ---- SpMM row body: 8 threads/row, 4 cols each; 16 gathers force-batched ---
__device__ __forceinline__ void spmm_row(const unsigned short* __restrict__ HWb,
                                         const int* __restrict__ rowPtr,
                                         const int* __restrict__ colIdx,
                                         const float* __restrict__ val,
                                         float* __restrict__ out,
                                         int n, int row, int cg)
{
    if (row >= n) return;
    const uint2* __restrict__ tbl = reinterpret_cast<const uint2*>(HWb);
    const int start = rowPtr[row];
    const int end   = rowPtr[row + 1];
    float a0 = 0.f, a1 = 0.f, a2 = 0.f, a3 = 0.f;

    #define ACC(G, V)                                                        \
        a0 = fmaf(V, __uint_as_float((G).x << 16), a0);                      \
        a1 = fmaf(V, __uint_as_float((G).x & 0xffff0000u), a1);              \
        a2 = fmaf(V, __uint_as_float((G).y << 16), a2);                      \
        a3 = fmaf(V, __uint_as_float((G).y & 0xffff0000u), a3);

    if (end - start == 16 && (start & 3) == 0) {
        const int4*   ci = reinterpret_cast<const int4*>(colIdx + start);
        const float4* vv = reinterpret_cast<const float4*>(val + start);
        const int4   c0 = ci[0], c1 = ci[1], c2 = ci[2], c3 = ci[3];
        const float4 v0 = vv[0], v1 = vv[1], v2 = vv[2], v3 = vv[3];
        // all 16 gathers issued before any consumption
        const uint2 g0  = tbl[c0.x * 8 + cg], g1  = tbl[c0.y * 8 + cg];
        const uint2 g2  = tbl[c0.z * 8 + cg], g3  = tbl[c0.w * 8 + cg];
        const uint2 g4  = tbl[c1.x * 8 + cg], g5  = tbl[c1.y * 8 + cg];
        const uint2 g6  = tbl[c1.z * 8 + cg], g7  = tbl[c1.w * 8 + cg];
        const uint2 g8  = tbl[c2.x * 8 + cg], g9  = tbl[c2.y * 8 + cg];
        const uint2 g10 = tbl[c2.z * 8 + cg], g11 = tbl[c2.w * 8 + cg];
        const uint2 g12 = tbl[c3.x * 8 + cg], g13 = tbl[c3.y * 8 + cg];
        const uint2 g14 = tbl[c3.z * 8 + cg], g15 = tbl[c3.w * 8 + cg];
        // reference accumulation order (ascending edge)
        ACC(g0,  v0.x) ACC(g1,  v0.y) ACC(g2,  v0.z) ACC(g3,  v0.w)
        ACC(g4,  v1.x) ACC(g5,  v1.y) ACC(g6,  v1.z) ACC(g7,  v1.w)
        ACC(g8,  v2.x) ACC(g9,  v2.y) ACC(g10, v2.z) ACC(g11, v2.w)
        ACC(g12, v3.x) ACC(g13, v3.y) ACC(g14, v3.z) ACC(g15, v3.w)
    } else {
        for (int e = start; e < end; ++e) {
            const int   c = colIdx[e];
            const float v = val[e];
            const uint2 g = tbl[c * 8 + cg];
            ACC(g, v)
        }
    }
    #undef ACC

    reinterpret_cast<float4*>(out)[(size_t)row * 8 + cg] =
        make_float4(a0, a1, a2, a3);
}

// ---------------- Kernel 1: HWb = bf16(H @ W) via MFMA ----------------------
__global__ __launch_bounds__(256) void gemm_mfma_kernel(
    const float* __restrict__ H, const float* __restrict__ W,
    unsigned short* __restrict__ HWb, int n)
{
    const int lane = threadIdx.x & 63;
    const int w    = threadIdx.x >> 6;
    bf16x8 bfrag[2][4];
    build_bfrag(W, lane, bfrag);
    int rb = blockIdx.x * 64 + w * 16;
    if (rb + 16 > n) rb = n - 16;      // tail overlap: identical values, benign
    gemm_tile(H, HWb, rb, lane, bfrag);
}

// ---------------- Kernel 2: out = A_csr @ HWb -------------------------------
__global__ __launch_bounds__(256) void spmm_kernel(
    const unsigned short* __restrict__ HWb, const int* __restrict__ rowPtr,
    const int* __restrict__ colIdx, const float* __restrict__ val,
    float* __restrict__ out, int n)
{
    const int gid = blockIdx.x * 256 + threadIdx.x;
    spmm_row(HWb, rowPtr, colIdx, val, out, n, gid >> 3, gid & 7);
}

// ---------------- Fallback: fused f32 (ws too small or n < 16) --------------
__global__ __launch_bounds__(256) void fused_kernel(
    const float* __restrict__ H, const float* __restrict__ W,
    const int* __restrict__ rowPtr, const int* __restrict__ colIdx,
    const float* __restrict__ val, float* __restrict__ out, int n)
{
    __shared__ float Wlds[DIN * DOUT];
    for (int i = threadIdx.x; i < DIN * DOUT; i += 256) Wlds[i] = W[i];
    __syncthreads();

    const int gid = blockIdx.x * 256 + threadIdx.x;
    const int row = gid >> 5;
    if (row >= n) return;
    const int c = gid & 31;

    const int start = rowPtr[row];
    const int end   = rowPtr[row + 1];
    float acc = 0.f;
    for (int e = start; e < end; ++e) {
        const int   cidx = colIdx[e];
        const float v    = val[e];
        const float* h = H + (size_t)cidx * DIN;
        float dot = 0.f;
        #pragma unroll 8
        for (int k = 0; k < DIN; ++k)
            dot = fmaf(h[k], Wlds[k * DOUT + c], dot);
        acc = fmaf(v, dot, acc);
    }
    out[(size_t)row * DOUT + c] = acc;
}

extern "C" void kernel_launch(void* const* d_in, const int* in_sizes, int n_in,
                              void* d_out, int out_size, void* d_ws, size_t ws_size,
                              hipStream_t stream)
{
    const float* H      = (const float*)d_in[0];
    const float* W      = (const float*)d_in[1];
    const int*   rowPtr = (const int*)d_in[2];
    const int*   colIdx = (const int*)d_in[3];
    const float* val    = (const float*)d_in[4];
    float*       out    = (float*)d_out;

    const int n = in_sizes[2] - 1;           // rowPtr has N+1 entries
    const size_t hw_bytes = (size_t)n * DOUT * sizeof(unsigned short);

    if (ws_size >= hw_bytes && n >= 16) {
        unsigned short* HWb = (unsigned short*)d_ws;
        gemm_mfma_kernel<<<(n + 63) / 64, 256, 0, stream>>>(H, W, HWb, n);
        const int spmm_blocks = (int)(((size_t)n * 8 + 255) / 256);
        spmm_kernel<<<spmm_blocks, 256, 0, stream>>>(HWb, rowPtr, colIdx, val, out, n);
    } else {
        const int blocks = (int)(((size_t)n * DOUT + 255) / 256);
        fused_kernel<<<blocks, 256, 0, stream>>>(H, W, rowPtr, colIdx, val, out, n);
    }
}